// Round 9
// baseline (55.198 us; speedup 1.0000x reference)
//
#include <hip/hip_runtime.h>

// Problem constants (fixed by setup_inputs)
#define P_    1024          // H*W
#define KLEN  9
#define S_    8
#define N1_   36            // B1*KLEN
#define WP    34            // W + 2*pad
#define HH    32
#define WW    32
#define SPLIT 16            // split of the 128 (b0,c) pairs (R2-proven)
#define BCPB  8             // (B0*C)/SPLIT pairs per block
#define THREADS 256
#define LOG2E 1.4426950408889634f
#define CPAD  32            // u32 stride per done-counter: one 128B line each

// d_ws layout: 3 partial banks of N1_*SPLIT*8 floats, then padded done counters.
#define PBANK    (N1_ * SPLIT * S_)       // 4608 floats
#define CTRL_OFF (3 * PBANK)              // float offset of control block

struct SharedBufs {
    float red[4][8];
    float vsh[8];
    int   last;
};

// Agent-scope RELAXED accesses: coherent across XCDs, but NO acquire/release
// cache maintenance (no L2 writeback/invalidate). Ordering is provided by
// __syncthreads (vmcnt drain) + data dependence, per the round-7/8 lesson.
__device__ __forceinline__ float agent_loadf(const float* p) {
    return __hip_atomic_load(p, __ATOMIC_RELAXED, __HIP_MEMORY_SCOPE_AGENT);
}
__device__ __forceinline__ void agent_storef(float* p, float v) {
    __hip_atomic_store(p, v, __ATOMIC_RELAXED, __HIP_MEMORY_SCOPE_AGENT);
}

// Block-reduce acc[8] across 256 threads; store partial to out[slot*8+s].
template <bool AGENT>
__device__ __forceinline__ void block_reduce_store(SharedBufs& sh, float acc[8],
                                                   int slot, float* __restrict__ out) {
    int tid = threadIdx.x;
    int lane = tid & 63, wid = tid >> 6;
#pragma unroll
    for (int s = 0; s < 8; ++s) {
        float v = acc[s];
#pragma unroll
        for (int off = 32; off >= 1; off >>= 1) v += __shfl_down(v, off, 64);
        if (lane == 0) sh.red[wid][s] = v;
    }
    __syncthreads();
    if (tid < 8) {
        float t = sh.red[0][tid] + sh.red[1][tid] + sh.red[2][tid] + sh.red[3][tid];
        if (AGENT) agent_storef(&out[slot * 8 + tid], t);
        else       out[slot * 8 + tid] = t;
    }
}

// vp[8] = squash(scale * sum_i part[(n1*SPLIT+i)*8+s]); plain loads (previous
// kernel's stores are visible across the kernel boundary). Staged through LDS.
__device__ __forceinline__ void load_squash(SharedBufs& sh, const float* __restrict__ part,
                                            int n1, float scale, float vp[8]) {
    int tid = threadIdx.x;
    if (tid < 8) {
        float v = 0.f;
#pragma unroll
        for (int i = 0; i < SPLIT; ++i) v += part[(n1 * SPLIT + i) * 8 + tid];
        sh.vsh[tid] = v;
    }
    __syncthreads();
    float n2 = 0.f;
#pragma unroll
    for (int s = 0; s < 8; ++s) { vp[s] = sh.vsh[s] * scale; n2 += vp[s] * vp[s]; }
    float f = (n2 / (1.f + n2)) * rsqrtf(n2 + 1e-8f);
#pragma unroll
    for (int s = 0; s < 8; ++s) vp[s] *= f;
    __syncthreads();   // vsh safe for reuse
}

// Decode the 4 p-positions this thread owns into x-plane offsets.
__device__ __forceinline__ void decode_offsets(const int* __restrict__ indexm,
                                               int k, int tid, int offhw[4]) {
#pragma unroll
    for (int j = 0; j < 4; ++j) {
        int p = tid + j * THREADS;
        int idx = indexm[k * P_ + p];
        int r = idx / WP, cc = idx - r * WP;
        int ir = r - 1, ic = cc - 1;
        offhw[j] = (ir >= 0 && ir < HH && ic >= 0 && ic < WW) ? ir * WW + ic : -1;
    }
}

__device__ __forceinline__ float gather_g(const float* __restrict__ x, int b1, int bc,
                                          const int offhw[4], int j) {
    int b0 = bc >> 6, c = bc & 63;
    const float* xc = x + ((((b0 << 2) + b1) << 6) + c) * P_;
    return (offhw[j] >= 0) ? xc[offhw[j]] : 0.f;
}

// acc[s] += sum over owned elements of u_s * softmax_s(u*vp)  (log2e folded in)
__device__ __forceinline__ void route_acc(const float* __restrict__ x,
                                          const float* __restrict__ wgt,
                                          int b1, int k, int bc0, const int offhw[4],
                                          const float vp[8], float acc[8]) {
#pragma unroll
    for (int i = 0; i < BCPB; ++i) {
        int bc = bc0 + i;
        int c = bc & 63;
        const float* wc = wgt + c * (KLEN * S_) + k * S_;
        float w[8], wv[8];
#pragma unroll
        for (int s = 0; s < 8; ++s) { w[s] = wc[s]; wv[s] = w[s] * vp[s] * LOG2E; }
#pragma unroll
        for (int j = 0; j < 4; ++j) {
            float g = gather_g(x, b1, bc, offhw, j);
            // |g*w*vp| < ~0.5 -> softmax without max-subtraction is safe.
            float e[8]; float Z = 0.f;
#pragma unroll
            for (int s = 0; s < 8; ++s) { e[s] = __builtin_amdgcn_exp2f(g * wv[s]); Z += e[s]; }
            float sc = g * __builtin_amdgcn_rcpf(Z);   // u_s*c_s = (g*w_s)*(e_s/Z)
#pragma unroll
            for (int s = 0; s < 8; ++s) acc[s] += sc * w[s] * e[s];
        }
    }
}

// ---- node 1: P1 partials; also zero the done counters used by node 3.
__global__ __launch_bounds__(THREADS)
void pass_uniform(const float* __restrict__ x, const float* __restrict__ wgt,
                  const int* __restrict__ indexm, float* __restrict__ P1,
                  unsigned* __restrict__ done) {
    __shared__ SharedBufs sh;
    const int split = blockIdx.x, n1 = blockIdx.y, tid = threadIdx.x;
    const int k = n1 % KLEN, b1 = n1 / KLEN;
    const int bc0 = split * BCPB;

    if (split == 0 && tid == 0)
        __hip_atomic_store(&done[n1 * CPAD], 0u, __ATOMIC_RELAXED, __HIP_MEMORY_SCOPE_AGENT);

    int offhw[4];
    decode_offsets(indexm, k, tid, offhw);

    float acc[8] = {0.f,0.f,0.f,0.f,0.f,0.f,0.f,0.f};
#pragma unroll
    for (int i = 0; i < BCPB; ++i) {
        int bc = bc0 + i;
        int c = bc & 63;
        const float* wc = wgt + c * (KLEN * S_) + k * S_;
        float w[8];
#pragma unroll
        for (int s = 0; s < 8; ++s) w[s] = wc[s];
#pragma unroll
        for (int j = 0; j < 4; ++j) {
            float g = gather_g(x, b1, bc, offhw, j);
#pragma unroll
            for (int s = 0; s < 8; ++s) acc[s] += g * w[s];
        }
    }
    block_reduce_store<false>(sh, acc, n1 * SPLIT + split, P1);
}

// ---- node 2: v1 = squash(sum(P1)/8); P2 partials.
__global__ __launch_bounds__(THREADS)
void pass_route2(const float* __restrict__ x, const float* __restrict__ wgt,
                 const int* __restrict__ indexm, const float* __restrict__ P1,
                 float* __restrict__ P2) {
    __shared__ SharedBufs sh;
    const int split = blockIdx.x, n1 = blockIdx.y, tid = threadIdx.x;
    const int k = n1 % KLEN, b1 = n1 / KLEN;
    const int bc0 = split * BCPB;

    float vp[8];
    load_squash(sh, P1, n1, 0.125f, vp);

    int offhw[4];
    decode_offsets(indexm, k, tid, offhw);

    float acc[8] = {0.f,0.f,0.f,0.f,0.f,0.f,0.f,0.f};
    route_acc(x, wgt, b1, k, bc0, offhw, vp, acc);
    block_reduce_store<false>(sh, acc, n1 * SPLIT + split, P2);
}

// ---- node 3: v2 = squash(sum(P2)); P3 partials; last-arrival block finalizes.
// All cross-block traffic is RELAXED agent scope; ordering via __syncthreads
// (vmcnt drain before the arrival RMW) + the RMW count reaching SPLIT.
__global__ __launch_bounds__(THREADS)
void pass_route3_fin(const float* __restrict__ x, const float* __restrict__ wgt,
                     const int* __restrict__ indexm, const float* __restrict__ P2,
                     float* __restrict__ P3, unsigned* __restrict__ done,
                     float* __restrict__ out) {
    __shared__ SharedBufs sh;
    const int split = blockIdx.x, n1 = blockIdx.y, tid = threadIdx.x;
    const int k = n1 % KLEN, b1 = n1 / KLEN;
    const int bc0 = split * BCPB;

    float vp[8];
    load_squash(sh, P2, n1, 1.0f, vp);

    int offhw[4];
    decode_offsets(indexm, k, tid, offhw);

    float acc[8] = {0.f,0.f,0.f,0.f,0.f,0.f,0.f,0.f};
    route_acc(x, wgt, b1, k, bc0, offhw, vp, acc);
    block_reduce_store<true>(sh, acc, n1 * SPLIT + split, P3);

    // block_reduce_store ended with tid<8 agent stores; the __syncthreads below
    // makes wave 0 wait vmcnt(0), so those stores are at the coherence point
    // before tid 0's arrival RMW is issued.
    __syncthreads();
    if (tid == 0) {
        unsigned old = __hip_atomic_fetch_add(&done[n1 * CPAD], 1u, __ATOMIC_RELAXED,
                                              __HIP_MEMORY_SCOPE_AGENT);
        sh.last = (old == SPLIT - 1);
    }
    __syncthreads();   // orders the RMW result before the loads below
    if (sh.last) {
        if (tid < 8) {
            float v = 0.f;
#pragma unroll
            for (int i = 0; i < SPLIT; ++i)
                v += agent_loadf(&P3[(n1 * SPLIT + i) * 8 + tid]);
            sh.vsh[tid] = v;
        }
        __syncthreads();
        if (tid < 8) {
            float n2 = 0.f;
#pragma unroll
            for (int s = 0; s < 8; ++s) n2 += sh.vsh[s] * sh.vsh[s];
            float f = (n2 / (1.f + n2)) * rsqrtf(n2 + 1e-8f);
            out[n1 * 8 + tid] = sh.vsh[tid] * f * 0.5f + 0.5f;
        }
    }
}

extern "C" void kernel_launch(void* const* d_in, const int* in_sizes, int n_in,
                              void* d_out, int out_size, void* d_ws, size_t ws_size,
                              hipStream_t stream) {
    const float* x    = (const float*)d_in[0];
    const float* wgt  = (const float*)d_in[1];
    const int*   idxm = (const int*)d_in[2];
    float* ws = (float*)d_ws;
    float* P1 = ws;
    float* P2 = ws + PBANK;
    float* P3 = ws + 2 * PBANK;
    unsigned* done = (unsigned*)(ws + CTRL_OFF);

    dim3 grid(SPLIT, N1_);
    pass_uniform   <<<grid, THREADS, 0, stream>>>(x, wgt, idxm, P1, done);
    pass_route2    <<<grid, THREADS, 0, stream>>>(x, wgt, idxm, P1, P2);
    pass_route3_fin<<<grid, THREADS, 0, stream>>>(x, wgt, idxm, P2, P3, done, (float*)d_out);
}

// Round 10
// 38.659 us; speedup vs baseline: 1.4278x; 1.4278x over previous
//
#include <hip/hip_runtime.h>

// Problem constants (fixed by setup_inputs)
#define P_    1024          // H*W
#define KLEN  9
#define S_    8
#define N1_   36            // B1*KLEN
#define WP    34            // W + 2*pad
#define HH    32
#define WW    32
#define SPLIT 16            // split of the 128 (b0,c) pairs (R2-proven)
#define BCPB  8             // (B0*C)/SPLIT pairs per block
#define THREADS 256
#define LOG2E 1.4426950408889634f

// d_ws layout: 3 partial banks of N1_*SPLIT*8 floats. No control words, no atomics.
#define PBANK (N1_ * SPLIT * S_)          // 4608 floats per bank

// Block-reduce acc[8] across 256 threads, then STORE the block partial to
// out[(n1*SPLIT+split)*8 + s]. Plain stores; kernel boundary publishes them.
__device__ __forceinline__ void block_reduce_store(float acc[8], int n1, int split,
                                                   float* __restrict__ out) {
    __shared__ float red[4][8];
    int tid = threadIdx.x;
    int lane = tid & 63, wid = tid >> 6;
#pragma unroll
    for (int s = 0; s < 8; ++s) {
        float v = acc[s];
#pragma unroll
        for (int off = 32; off >= 1; off >>= 1) v += __shfl_down(v, off, 64);
        if (lane == 0) red[wid][s] = v;
    }
    __syncthreads();
    if (tid < 8) {
        float t = red[0][tid] + red[1][tid] + red[2][tid] + red[3][tid];
        out[(n1 * SPLIT + split) * 8 + tid] = t;
    }
}

// Decode the 4 p-positions this thread owns (p = tid + j*256) into x-plane offsets.
__device__ __forceinline__ void decode_offsets(const int* __restrict__ indexm,
                                               int k, int tid, int offhw[4]) {
#pragma unroll
    for (int j = 0; j < 4; ++j) {
        int p = tid + j * THREADS;
        int idx = indexm[k * P_ + p];     // index into flattened 34x34 padded map
        int r  = idx / WP;
        int cc = idx - r * WP;
        int ir = r - 1, ic = cc - 1;      // un-pad
        offhw[j] = (ir >= 0 && ir < HH && ic >= 0 && ic < WW) ? ir * WW + ic : -1;
    }
}

// Pass 1: partials of sum over (b0,c,p) of g * W  (uniform coupling folded in later)
__global__ __launch_bounds__(THREADS)
void pass_uniform(const float* __restrict__ x, const float* __restrict__ wgt,
                  const int* __restrict__ indexm, float* __restrict__ partOut) {
    int split = blockIdx.x;
    int n1 = blockIdx.y;
    int tid = threadIdx.x;
    int k = n1 % KLEN, b1 = n1 / KLEN;

    int offhw[4];
    decode_offsets(indexm, k, tid, offhw);

    float acc[8] = {0.f,0.f,0.f,0.f,0.f,0.f,0.f,0.f};
    for (int bc = split * BCPB; bc < split * BCPB + BCPB; ++bc) {
        int b0 = bc >> 6, c = bc & 63;
        const float* xc = x + ((((b0 << 2) + b1) << 6) + c) * P_;
        const float* wc = wgt + c * (KLEN * S_) + k * S_;
        float w[8];
#pragma unroll
        for (int s = 0; s < 8; ++s) w[s] = wc[s];
#pragma unroll
        for (int j = 0; j < 4; ++j) {
            float g = (offhw[j] >= 0) ? xc[offhw[j]] : 0.f;
#pragma unroll
            for (int s = 0; s < 8; ++s) acc[s] += g * w[s];
        }
    }
    block_reduce_store(acc, n1, split, partOut);
}

// Pass 2/3: vprev = squash(sum(prev partials)*scale);
// partials of sum over (b0,c,p) of u * softmax_s(u*vprev)
__global__ __launch_bounds__(THREADS)
void pass_route(const float* __restrict__ x, const float* __restrict__ wgt,
                const int* __restrict__ indexm, const float* __restrict__ partPrev,
                float prevScale, float* __restrict__ partOut) {
    int split = blockIdx.x;
    int n1 = blockIdx.y;
    int tid = threadIdx.x;
    int k = n1 % KLEN, b1 = n1 / KLEN;

    // Sum the 16 previous-pass partials (uniform addresses; L2-hot), then squash.
    float vp[8] = {0.f,0.f,0.f,0.f,0.f,0.f,0.f,0.f};
#pragma unroll
    for (int i = 0; i < SPLIT; ++i) {
        const float* pp = partPrev + (n1 * SPLIT + i) * 8;
#pragma unroll
        for (int s = 0; s < 8; ++s) vp[s] += pp[s];
    }
    float n2 = 0.f;
#pragma unroll
    for (int s = 0; s < 8; ++s) { vp[s] *= prevScale; n2 += vp[s] * vp[s]; }
    float f = (n2 / (1.f + n2)) * rsqrtf(n2 + 1e-8f);
#pragma unroll
    for (int s = 0; s < 8; ++s) vp[s] *= f;

    int offhw[4];
    decode_offsets(indexm, k, tid, offhw);

    float acc[8] = {0.f,0.f,0.f,0.f,0.f,0.f,0.f,0.f};
    for (int bc = split * BCPB; bc < split * BCPB + BCPB; ++bc) {
        int b0 = bc >> 6, c = bc & 63;
        const float* xc = x + ((((b0 << 2) + b1) << 6) + c) * P_;
        const float* wc = wgt + c * (KLEN * S_) + k * S_;
        float w[8], wv[8];
#pragma unroll
        for (int s = 0; s < 8; ++s) { w[s] = wc[s]; wv[s] = w[s] * vp[s] * LOG2E; }
#pragma unroll
        for (int j = 0; j < 4; ++j) {
            float g = (offhw[j] >= 0) ? xc[offhw[j]] : 0.f;
            // |g*w*vp| < ~0.5 -> softmax without max-subtraction is safe.
            float e[8]; float Z = 0.f;
#pragma unroll
            for (int s = 0; s < 8; ++s) { e[s] = __builtin_amdgcn_exp2f(g * wv[s]); Z += e[s]; }
            float sc = g * __builtin_amdgcn_rcpf(Z);  // u_s*c_s = (g*w_s)*(e_s/Z)
#pragma unroll
            for (int s = 0; s < 8; ++s) acc[s] += sc * w[s] * e[s];
        }
    }
    block_reduce_store(acc, n1, split, partOut);
}

__global__ void finalize_out(const float* __restrict__ part3, float* __restrict__ out) {
    int tid = threadIdx.x;
    if (tid < N1_) {
        float v[8] = {0.f,0.f,0.f,0.f,0.f,0.f,0.f,0.f};
#pragma unroll
        for (int i = 0; i < SPLIT; ++i) {
            const float* pp = part3 + (tid * SPLIT + i) * 8;
#pragma unroll
            for (int s = 0; s < 8; ++s) v[s] += pp[s];
        }
        float n2 = 0.f;
#pragma unroll
        for (int s = 0; s < 8; ++s) n2 += v[s] * v[s];
        float f = (n2 / (1.f + n2)) * rsqrtf(n2 + 1e-8f);
#pragma unroll
        for (int s = 0; s < 8; ++s) out[tid * 8 + s] = v[s] * f * 0.5f + 0.5f;
    }
}

extern "C" void kernel_launch(void* const* d_in, const int* in_sizes, int n_in,
                              void* d_out, int out_size, void* d_ws, size_t ws_size,
                              hipStream_t stream) {
    const float* x    = (const float*)d_in[0];
    const float* wgt  = (const float*)d_in[1];
    const int*   idxm = (const int*)d_in[2];
    float* ws = (float*)d_ws;
    float* P1 = ws;
    float* P2 = ws + PBANK;
    float* P3 = ws + 2 * PBANK;

    dim3 grid(SPLIT, N1_);
    pass_uniform<<<grid, THREADS, 0, stream>>>(x, wgt, idxm, P1);
    pass_route <<<grid, THREADS, 0, stream>>>(x, wgt, idxm, P1, 0.125f, P2);
    pass_route <<<grid, THREADS, 0, stream>>>(x, wgt, idxm, P2, 1.0f,   P3);
    finalize_out<<<1, 64, 0, stream>>>(P3, (float*)d_out);
}